// Round 4
// baseline (1559.498 us; speedup 1.0000x reference)
//
#include <hip/hip_runtime.h>
#include <math.h>

#define B_    4096
#define L_    16
#define E_    50
#define EP_   64
#define H_    512
#define G4_   2048
#define V_    128
#define VIS_  2048

typedef unsigned short ushortT;
typedef ushortT ushort8 __attribute__((ext_vector_type(8)));
typedef ushortT ushort4v __attribute__((ext_vector_type(4)));
typedef short   short8  __attribute__((ext_vector_type(8)));
typedef float   f32x4   __attribute__((ext_vector_type(4)));

__device__ __forceinline__ ushortT f2bf(float f) {
  union { float f; unsigned u; } v; v.f = f;
  unsigned u = v.u;
  u += 0x7fffu + ((u >> 16) & 1u);
  return (ushortT)(u >> 16);
}
__device__ __forceinline__ float bf2f(ushortT h) {
  union { unsigned u; float f; } v; v.u = ((unsigned)h) << 16;
  return v.f;
}
static inline ushortT f2bf_h(float f) {
  union { float f; unsigned u; } v; v.f = f;
  unsigned u = v.u;
  u += 0x7fffu + ((u >> 16) & 1u);
  return (ushortT)(u >> 16);
}

// ---------------------------------------------------------------- prep
__global__ void lengths_k(const int* __restrict__ text, int* __restrict__ lens) {
  int b = blockIdx.x * blockDim.x + threadIdx.x;
  if (b < B_) {
    int c = 0;
    for (int t = 0; t < L_; ++t) c += (text[b * L_ + t] != 0) ? 1 : 0;
    lens[b] = c;
  }
}

__global__ void stage_embs_k(const int* __restrict__ text, const float* __restrict__ emb,
                             ushortT* __restrict__ xs_enc, ushortT* __restrict__ xs_dec) {
  int idx = blockIdx.x * blockDim.x + threadIdx.x;
  const int total = L_ * B_ * EP_;
  if (idx >= total) return;
  int e = idx & 63;
  int r = idx >> 6;
  int b = r % B_;
  int t = r / B_;
  ushortT ve = 0, vd = 0;
  if (e < E_) {
    int id_enc = text[b * L_ + t];
    int id_dec = (t == 0) ? 0 : text[b * L_ + t - 1];
    ve = f2bf(emb[id_enc * E_ + e]);
    vd = f2bf(emb[id_dec * E_ + e]);
  }
  xs_enc[idx] = ve;
  xs_dec[idx] = vd;
}

// gate-interleaved: new row p = 4*j + q  <-  old row q*H + j  (q: i,f,g,o)
__global__ void prep_whh_k(const float* __restrict__ W, ushortT* __restrict__ D) {
  int idx = blockIdx.x * 256 + threadIdx.x;
  if (idx >= G4_ * H_) return;
  int k = idx & (H_ - 1), p = idx >> 9;
  int j = p >> 2, q = p & 3;
  D[idx] = f2bf(W[(size_t)(q * H_ + j) * H_ + k]);
}
__global__ void prep_wih_k(const float* __restrict__ W, ushortT* __restrict__ D) {
  int idx = blockIdx.x * 256 + threadIdx.x;
  if (idx >= G4_ * EP_) return;
  int k = idx & 63, p = idx >> 6;
  int j = p >> 2, q = p & 3;
  D[idx] = (k < E_) ? f2bf(W[(size_t)(q * H_ + j) * E_ + k]) : (ushortT)0;
}
__global__ void prep_bias_k(const float* __restrict__ bi, const float* __restrict__ bh,
                            float* __restrict__ D) {
  int p = blockIdx.x * 256 + threadIdx.x;
  if (p >= G4_) return;
  int j = p >> 2, q = p & 3;
  int o = q * H_ + j;
  D[p] = bi[o] + bh[o];
}
__global__ void cvt_k(const float* __restrict__ s, ushortT* __restrict__ d, int n) {
  int i = blockIdx.x * 256 + threadIdx.x;
  if (i < n) d[i] = f2bf(s[i]);
}
__global__ void cvt4_k(const float* __restrict__ s, ushortT* __restrict__ d, int n4) {
  int i = blockIdx.x * 256 + threadIdx.x;
  if (i >= n4) return;
  float4 v = ((const float4*)s)[i];
  ushort4v o;
  o[0] = f2bf(v.x); o[1] = f2bf(v.y); o[2] = f2bf(v.z); o[3] = f2bf(v.w);
  ((ushort4v*)d)[i] = o;
}
__global__ void fill_bf_k(ushortT* __restrict__ p, ushortT v, int n) {
  int i = blockIdx.x * blockDim.x + threadIdx.x;
  if (i < n) p[i] = v;
}
__global__ void fill_f_k(float* __restrict__ p, float v, int n) {
  int i = blockIdx.x * blockDim.x + threadIdx.x;
  if (i < n) p[i] = v;
}

// ---------------------------------------------------------------- generic bf16 MFMA NT-GEMM (sims)
__global__ __launch_bounds__(256)
void gemm_bf16_k(const ushortT* __restrict__ A, int lda, int K,
                 const ushortT* __restrict__ B, int ldb,
                 ushortT* __restrict__ Cb, int ldc) {
  __shared__ ushortT As[128 * 72];
  __shared__ ushortT Bs[128 * 72];
  const int tid = threadIdx.x;
  const int m0 = blockIdx.y * 128, n0 = blockIdx.x * 128;
  const int lane = tid & 63, wave = tid >> 6;
  const int wm = (wave >> 1) * 64, wn = (wave & 1) * 64;
  const int fr = lane & 15, kq = (lane >> 4) * 8;

  f32x4 acc[4][4];
#pragma unroll
  for (int i = 0; i < 4; ++i)
#pragma unroll
    for (int j = 0; j < 4; ++j)
#pragma unroll
      for (int r = 0; r < 4; ++r) acc[i][j][r] = 0.f;

  for (int k0 = 0; k0 < K; k0 += 64) {
#pragma unroll
    for (int l = 0; l < 4; ++l) {
      int e = tid + l * 256;
      int r = e >> 3, cc = (e & 7) * 8;
      *(ushort8*)(&As[r * 72 + cc]) = *(const ushort8*)(&A[(size_t)(m0 + r) * lda + k0 + cc]);
      *(ushort8*)(&Bs[r * 72 + cc]) = *(const ushort8*)(&B[(size_t)(n0 + r) * ldb + k0 + cc]);
    }
    __syncthreads();
#pragma unroll
    for (int kk = 0; kk < 2; ++kk) {
      short8 afr[4], bfr[4];
#pragma unroll
      for (int mi = 0; mi < 4; ++mi)
        afr[mi] = *(const short8*)(&As[(wm + mi * 16 + fr) * 72 + kk * 32 + kq]);
#pragma unroll
      for (int ni = 0; ni < 4; ++ni)
        bfr[ni] = *(const short8*)(&Bs[(wn + ni * 16 + fr) * 72 + kk * 32 + kq]);
#pragma unroll
      for (int mi = 0; mi < 4; ++mi)
#pragma unroll
        for (int ni = 0; ni < 4; ++ni)
          acc[mi][ni] = __builtin_amdgcn_mfma_f32_16x16x32_bf16(afr[mi], bfr[ni], acc[mi][ni], 0, 0, 0);
    }
    __syncthreads();
  }

#pragma unroll
  for (int mi = 0; mi < 4; ++mi)
#pragma unroll
    for (int r = 0; r < 4; ++r) {
      int m = m0 + wm + mi * 16 + (lane >> 4) * 4 + r;
#pragma unroll
      for (int ni = 0; ni < 4; ++ni) {
        int n = n0 + wn + ni * 16 + fr;
        Cb[(size_t)m * ldc + n] = f2bf(acc[mi][ni][r]);
      }
    }
}

// ---------------------------------------------------------------- split-K bf16 GEMM, atomic fp32 out
__global__ __launch_bounds__(256)
void gemm_splitk_k(const ushortT* __restrict__ A, int lda,
                   const ushortT* __restrict__ B, int ldb,
                   int kchunk, float* __restrict__ C, int ldc) {
  __shared__ ushortT As[128 * 72];
  __shared__ ushortT Bs[128 * 72];
  const int tid = threadIdx.x;
  const int m0 = blockIdx.y * 128, n0 = blockIdx.x * 128;
  const int kbeg = blockIdx.z * kchunk, kend = kbeg + kchunk;
  const int lane = tid & 63, wave = tid >> 6;
  const int wm = (wave >> 1) * 64, wn = (wave & 1) * 64;
  const int fr = lane & 15, kq = (lane >> 4) * 8;

  f32x4 acc[4][4];
#pragma unroll
  for (int i = 0; i < 4; ++i)
#pragma unroll
    for (int j = 0; j < 4; ++j)
#pragma unroll
      for (int r = 0; r < 4; ++r) acc[i][j][r] = 0.f;

  for (int k0 = kbeg; k0 < kend; k0 += 64) {
#pragma unroll
    for (int l = 0; l < 4; ++l) {
      int e = tid + l * 256;
      int r = e >> 3, cc = (e & 7) * 8;
      *(ushort8*)(&As[r * 72 + cc]) = *(const ushort8*)(&A[(size_t)(m0 + r) * lda + k0 + cc]);
      *(ushort8*)(&Bs[r * 72 + cc]) = *(const ushort8*)(&B[(size_t)(n0 + r) * ldb + k0 + cc]);
    }
    __syncthreads();
#pragma unroll
    for (int kk = 0; kk < 2; ++kk) {
      short8 afr[4], bfr[4];
#pragma unroll
      for (int mi = 0; mi < 4; ++mi)
        afr[mi] = *(const short8*)(&As[(wm + mi * 16 + fr) * 72 + kk * 32 + kq]);
#pragma unroll
      for (int ni = 0; ni < 4; ++ni)
        bfr[ni] = *(const short8*)(&Bs[(wn + ni * 16 + fr) * 72 + kk * 32 + kq]);
#pragma unroll
      for (int mi = 0; mi < 4; ++mi)
#pragma unroll
        for (int ni = 0; ni < 4; ++ni)
          acc[mi][ni] = __builtin_amdgcn_mfma_f32_16x16x32_bf16(afr[mi], bfr[ni], acc[mi][ni], 0, 0, 0);
    }
    __syncthreads();
  }

#pragma unroll
  for (int mi = 0; mi < 4; ++mi)
#pragma unroll
    for (int r = 0; r < 4; ++r) {
      int m = m0 + wm + mi * 16 + (lane >> 4) * 4 + r;
#pragma unroll
      for (int ni = 0; ni < 4; ++ni) {
        int n = n0 + wn + ni * 16 + fr;
        atomicAdd(&C[(size_t)m * ldc + n], acc[mi][ni][r]);
      }
    }
}

// ---------------------------------------------------------------- barrier-free fused LSTM step
// Block: 256 batch-rows x 64 gate-cols. Weights slice in LDS (fragment order),
// A-fragments direct from global/L2. No barriers in K-loop.
__global__ __launch_bounds__(256, 2)
void lstm2_k(const ushortT* __restrict__ hin, const ushortT* __restrict__ Whh,
             const ushortT* __restrict__ xs,  const ushortT* __restrict__ Wih,
             const float* __restrict__ biasc,
             float* __restrict__ c, ushortT* __restrict__ hout,
             ushortT* __restrict__ sel, const int* __restrict__ lens, int t) {
  __shared__ ushortT wlds[18 * 4 * 64 * 8];   // 73728 B
  const int tid = threadIdx.x;
  const int n0 = blockIdx.x * 64;             // gate-col base
  const int m0 = blockIdx.y * 256;            // batch-row base
  const int lane = tid & 63, wave = tid >> 6;
  const int am = lane & 15, ak = (lane >> 4) * 8;
  const int wrow = m0 + wave * 64;

  // stage weight slice into LDS in fragment order: frag (ks, ni) at ((ks*4+ni)*64+lane)*8
#pragma unroll
  for (int i = 0; i < 18; ++i) {
    int idx = i * 256 + tid;                  // 0..4607
    int ks = idx >> 8;
    int rem = idx & 255;
    int ni = rem >> 6, ln = rem & 63;
    int row = n0 + ni * 16 + (ln & 15);
    int kc = (ln >> 4) * 8;
    ushort8 vv;
    if (ks < 16) vv = *(const ushort8*)(&Whh[(size_t)row * H_ + ks * 32 + kc]);
    else         vv = *(const ushort8*)(&Wih[(size_t)row * EP_ + (ks - 16) * 32 + kc]);
    *(ushort8*)(&wlds[(size_t)idx * 8]) = vv;
  }
  __syncthreads();

  f32x4 acc[4][4];
#pragma unroll
  for (int i = 0; i < 4; ++i)
#pragma unroll
    for (int j = 0; j < 4; ++j)
#pragma unroll
      for (int r = 0; r < 4; ++r) acc[i][j][r] = 0.f;

#pragma unroll 4
  for (int ks = 0; ks < 16; ++ks) {
    short8 a[4];
#pragma unroll
    for (int mi = 0; mi < 4; ++mi)
      a[mi] = *(const short8*)(&hin[(size_t)(wrow + mi * 16 + am) * H_ + ks * 32 + ak]);
#pragma unroll
    for (int ni = 0; ni < 4; ++ni) {
      short8 b = *(const short8*)(&wlds[((ks * 4 + ni) * 64 + lane) * 8]);
#pragma unroll
      for (int mi = 0; mi < 4; ++mi)
        acc[mi][ni] = __builtin_amdgcn_mfma_f32_16x16x32_bf16(a[mi], b, acc[mi][ni], 0, 0, 0);
    }
  }
#pragma unroll
  for (int ks = 0; ks < 2; ++ks) {
    short8 a[4];
#pragma unroll
    for (int mi = 0; mi < 4; ++mi)
      a[mi] = *(const short8*)(&xs[(size_t)(wrow + mi * 16 + am) * EP_ + ks * 32 + ak]);
#pragma unroll
    for (int ni = 0; ni < 4; ++ni) {
      short8 b = *(const short8*)(&wlds[(((16 + ks) * 4 + ni) * 64 + lane) * 8]);
#pragma unroll
      for (int mi = 0; mi < 4; ++mi)
        acc[mi][ni] = __builtin_amdgcn_mfma_f32_16x16x32_bf16(a[mi], b, acc[mi][ni], 0, 0, 0);
    }
  }

  // epilogue: stage wave's 64x64 fp32 tile (stride 68), then fused cell update
  __syncthreads();                            // all waves done reading wlds
  float* gw = (float*)wlds + wave * 64 * 68;  // 17408 B per wave
#pragma unroll
  for (int mi = 0; mi < 4; ++mi)
#pragma unroll
    for (int r = 0; r < 4; ++r) {
      int rowL = mi * 16 + (lane >> 4) * 4 + r;
#pragma unroll
      for (int ni = 0; ni < 4; ++ni)
        gw[rowL * 68 + ni * 16 + am] = acc[mi][ni][r];
    }
  // same-wave LDS RAW: compiler inserts lgkmcnt waits
  const int jg0 = n0 >> 2;                    // h-col base (16 cols)
#pragma unroll
  for (int p = 0; p < 16; ++p) {
    int idx = p * 64 + lane;                  // 0..1023
    int rowL = idx >> 4, j = idx & 15;
    f32x4 g  = *(const f32x4*)(&gw[rowL * 68 + j * 4]);
    f32x4 bb = *(const f32x4*)(&biasc[(jg0 + j) * 4]);
    int brow = wrow + rowL;
    size_t ci = (size_t)brow * H_ + jg0 + j;
    float ig = g[0] + bb[0], fg = g[1] + bb[1], gg = g[2] + bb[2], og = g[3] + bb[3];
    float si = 1.f / (1.f + expf(-ig));
    float sf = 1.f / (1.f + expf(-fg));
    float so = 1.f / (1.f + expf(-og));
    float cn = sf * c[ci] + si * tanhf(gg);
    float hn = so * tanhf(cn);
    c[ci] = cn;
    hout[ci] = f2bf(hn);
    if (sel) {
      int len = lens[brow];
      int eff = (len == 0) ? L_ : len;
      if (t == eff - 1) sel[ci] = f2bf(hn);
    }
  }
}

// ---------------------------------------------------------------- decoder logits + NLL
// 256 blocks x 16 rows; 4 waves split K; LDS reduce; in-register log-softmax.
__global__ __launch_bounds__(256)
void dec_loss2_k(const ushortT* __restrict__ h, const ushortT* __restrict__ Wout,
                 const int* __restrict__ text, int t, float* __restrict__ out) {
  __shared__ float pbuf[4 * 16 * 132];        // 33792 B
  const int tid = threadIdx.x;
  const int row0 = blockIdx.x * 16;
  const int lane = tid & 63, wave = tid >> 6;
  const int am = lane & 15, ak = (lane >> 4) * 8;

  f32x4 acc[8];
#pragma unroll
  for (int i = 0; i < 8; ++i)
#pragma unroll
    for (int r = 0; r < 4; ++r) acc[i][r] = 0.f;

#pragma unroll
  for (int ks = 0; ks < 4; ++ks) {
    int kk = wave * 128 + ks * 32;
    short8 a = *(const short8*)(&h[(size_t)(row0 + am) * H_ + kk + ak]);
#pragma unroll
    for (int nf = 0; nf < 8; ++nf) {
      short8 b = *(const short8*)(&Wout[(size_t)(nf * 16 + am) * H_ + kk + ak]);
      acc[nf] = __builtin_amdgcn_mfma_f32_16x16x32_bf16(a, b, acc[nf], 0, 0, 0);
    }
  }
#pragma unroll
  for (int nf = 0; nf < 8; ++nf)
#pragma unroll
    for (int r = 0; r < 4; ++r) {
      int rowL = (lane >> 4) * 4 + r;
      pbuf[(wave * 16 + rowL) * 132 + nf * 16 + am] = acc[nf][r];
    }
  __syncthreads();

  int row = tid >> 4, lp = tid & 15;          // row 0..15, 16 threads/row
  f32x4 s0, s1;
#pragma unroll
  for (int r = 0; r < 4; ++r) { s0[r] = 0.f; s1[r] = 0.f; }
#pragma unroll
  for (int wv = 0; wv < 4; ++wv) {
    s0 += *(const f32x4*)(&pbuf[(wv * 16 + row) * 132 + lp * 8]);
    s1 += *(const f32x4*)(&pbuf[(wv * 16 + row) * 132 + lp * 8 + 4]);
  }
  float mx = s0[0];
#pragma unroll
  for (int r = 1; r < 4; ++r) mx = fmaxf(mx, s0[r]);
#pragma unroll
  for (int r = 0; r < 4; ++r) mx = fmaxf(mx, s1[r]);
#pragma unroll
  for (int d = 1; d < 16; d <<= 1) mx = fmaxf(mx, __shfl_xor(mx, d));
  float sum = 0.f;
#pragma unroll
  for (int r = 0; r < 4; ++r) sum += expf(s0[r] - mx) + expf(s1[r] - mx);
#pragma unroll
  for (int d = 1; d < 16; d <<= 1) sum += __shfl_xor(sum, d);
  float lse = mx + logf(sum);
  int b = row0 + row;
  int tgt = text[b * L_ + t];
  if ((tgt >> 3) == lp) {
    float lv = (tgt & 4) ? s1[tgt & 3] : s0[tgt & 3];
    float loss = (lse - lv) * (1.f / (float)L_);
    if (t == 0) out[b] = loss;
    else out[b] += loss;
  }
}

// ---------------------------------------------------------------- norms
__global__ void rownorm_f2b_k(const float* __restrict__ x, ushortT* __restrict__ xb, int n) {
  int b = blockIdx.x, tid = threadIdx.x;
  const float* row = x + (size_t)b * n;
  float s = 0.f;
  for (int i = tid; i < n; i += 256) { float v = row[i]; s += v * v; }
  __shared__ float red[256];
  red[tid] = s; __syncthreads();
  for (int st = 128; st > 0; st >>= 1) { if (tid < st) red[tid] += red[tid + st]; __syncthreads(); }
  float inv = 1.f / sqrtf(red[0]);
  for (int i = tid; i < n; i += 256) xb[(size_t)b * n + i] = f2bf(row[i] * inv);
}

// tenc: bias + relu + rownorm -> bf16
__global__ void bias_relu_rownorm_k(const float* __restrict__ x, const float* __restrict__ bias,
                                    ushortT* __restrict__ xb, int n) {
  int b = blockIdx.x, tid = threadIdx.x;
  const float* row = x + (size_t)b * n;
  float vv[2];
  float s = 0.f;
  for (int l = 0; l < 2; ++l) {
    int i = tid + l * 256;
    float v = fmaxf(row[i] + bias[i], 0.f);
    vv[l] = v; s += v * v;
  }
  __shared__ float red[256];
  red[tid] = s; __syncthreads();
  for (int st = 128; st > 0; st >>= 1) { if (tid < st) red[tid] += red[tid + st]; __syncthreads(); }
  float inv = 1.f / sqrtf(red[0]);
  for (int l = 0; l < 2; ++l) xb[(size_t)b * n + tid + l * 256] = f2bf(vv[l] * inv);
}

// hatt: rownorm -> bf16 h0 + fp32 c0
__global__ void rownorm_fcb_k(const float* __restrict__ x, ushortT* __restrict__ xb,
                              float* __restrict__ c2, int n) {
  int b = blockIdx.x, tid = threadIdx.x;
  const float* row = x + (size_t)b * n;
  float s = 0.f;
  for (int i = tid; i < n; i += 256) { float v = row[i]; s += v * v; }
  __shared__ float red[256];
  red[tid] = s; __syncthreads();
  for (int st = 128; st > 0; st >>= 1) { if (tid < st) red[tid] += red[tid + st]; __syncthreads(); }
  float inv = 1.f / sqrtf(red[0]);
  for (int i = tid; i < n; i += 256) {
    float v = row[i] * inv;
    xb[(size_t)b * n + i] = f2bf(v);
    c2[(size_t)b * n + i] = v;
  }
}

__global__ __launch_bounds__(256)
void softmax_bf_rows_k(ushortT* __restrict__ P) {
  int r = blockIdx.x, tid = threadIdx.x;
  ushortT* row = P + (size_t)r * B_;
  float xv[16];
  float m = -1e30f;
#pragma unroll
  for (int l = 0; l < 16; ++l) { float v = bf2f(row[tid + l * 256]); xv[l] = v; m = fmaxf(m, v); }
  __shared__ float red[256];
  red[tid] = m; __syncthreads();
  for (int st = 128; st > 0; st >>= 1) { if (tid < st) red[tid] = fmaxf(red[tid], red[tid + st]); __syncthreads(); }
  m = red[0]; __syncthreads();
  float s = 0.f;
#pragma unroll
  for (int l = 0; l < 16; ++l) { float e = expf(xv[l] - m); xv[l] = e; s += e; }
  red[tid] = s; __syncthreads();
  for (int st = 128; st > 0; st >>= 1) { if (tid < st) red[tid] += red[tid + st]; __syncthreads(); }
  float inv = 1.f / red[0];
#pragma unroll
  for (int l = 0; l < 16; ++l) row[tid + l * 256] = f2bf(xv[l] * inv);
}

__global__ void transpose_bf_k(const ushortT* __restrict__ in, ushortT* __restrict__ out,
                               int R, int Ccols) {
  __shared__ ushortT tile[32][33];
  int c0 = blockIdx.x * 32, r0 = blockIdx.y * 32;
  int tx = threadIdx.x & 31, ty = threadIdx.x >> 5;
  for (int i = ty; i < 32; i += 8) tile[i][tx] = in[(size_t)(r0 + i) * Ccols + c0 + tx];
  __syncthreads();
  for (int i = ty; i < 32; i += 8) out[(size_t)(c0 + i) * R + r0 + tx] = tile[tx][i];
}

// ================================================================ launch
extern "C" void kernel_launch(void* const* d_in, const int* in_sizes, int n_in,
                              void* d_out, int out_size, void* d_ws, size_t ws_size,
                              hipStream_t stream) {
  const float* visual = (const float*)d_in[0];
  const int*   text   = (const int*)  d_in[1];
  const float* emb    = (const float*)d_in[2];
  const float* W_ih   = (const float*)d_in[3];
  const float* W_hh   = (const float*)d_in[4];
  const float* b_ih   = (const float*)d_in[5];
  const float* b_hh   = (const float*)d_in[6];
  const float* W_enc  = (const float*)d_in[7];
  const float* b_enc  = (const float*)d_in[8];
  const float* W_out  = (const float*)d_in[9];
  const float* W_vis  = (const float*)d_in[10];
  float* out = (float*)d_out;

  char* w = (char*)d_ws;
  auto alloc = [&](size_t bytes) { char* p = w; w += (bytes + 255) & ~(size_t)255; return p; };
  ushortT* xs_enc  = (ushortT*)alloc((size_t)L_ * B_ * EP_ * 2);
  ushortT* xs_dec  = (ushortT*)alloc((size_t)L_ * B_ * EP_ * 2);
  ushortT* Whhbf   = (ushortT*)alloc((size_t)G4_ * H_ * 2);
  ushortT* Wihbf   = (ushortT*)alloc((size_t)G4_ * EP_ * 2);
  float*   biasc   = (float*)  alloc((size_t)G4_ * 4);
  ushortT* Wvisbf  = (ushortT*)alloc((size_t)H_ * VIS_ * 2);
  ushortT* Wencbf  = (ushortT*)alloc((size_t)H_ * H_ * 2);
  ushortT* Woutbf  = (ushortT*)alloc((size_t)V_ * H_ * 2);
  ushortT* visbf   = (ushortT*)alloc((size_t)B_ * VIS_ * 2);
  ushortT* henc0   = (ushortT*)alloc((size_t)B_ * H_ * 2);
  ushortT* henc1   = (ushortT*)alloc((size_t)B_ * H_ * 2);
  float*   cenc    = (float*)  alloc((size_t)B_ * H_ * 4);
  ushortT* selbf   = (ushortT*)alloc((size_t)B_ * H_ * 2);
  float*   vf      = (float*)  alloc((size_t)B_ * H_ * 4);
  ushortT* vbf     = (ushortT*)alloc((size_t)B_ * H_ * 2);
  float*   tencf   = (float*)  alloc((size_t)B_ * H_ * 4);
  ushortT* tencbf  = (ushortT*)alloc((size_t)B_ * H_ * 2);
  ushortT* Pbf     = (ushortT*)alloc((size_t)B_ * B_ * 2);
  ushortT* Vtbf    = (ushortT*)alloc((size_t)H_ * B_ * 2);
  float*   hatt    = (float*)  alloc((size_t)B_ * H_ * 4);
  float*   cdec    = (float*)  alloc((size_t)B_ * H_ * 4);
  ushortT* hdec0   = (ushortT*)alloc((size_t)B_ * H_ * 2);
  ushortT* hdec1   = (ushortT*)alloc((size_t)B_ * H_ * 2);
  int*     lens    = (int*)    alloc((size_t)B_ * 4);

  const int BH = B_ * H_;

  lengths_k<<<dim3((B_ + 255) / 256), dim3(256), 0, stream>>>(text, lens);
  stage_embs_k<<<dim3((L_ * B_ * EP_) / 256), dim3(256), 0, stream>>>(text, emb, xs_enc, xs_dec);
  prep_whh_k<<<dim3((G4_ * H_) / 256), dim3(256), 0, stream>>>(W_hh, Whhbf);
  prep_wih_k<<<dim3((G4_ * EP_) / 256), dim3(256), 0, stream>>>(W_ih, Wihbf);
  prep_bias_k<<<dim3(G4_ / 256), dim3(256), 0, stream>>>(b_ih, b_hh, biasc);
  cvt_k<<<dim3((H_ * VIS_) / 256), dim3(256), 0, stream>>>(W_vis, Wvisbf, H_ * VIS_);
  cvt_k<<<dim3((H_ * H_) / 256),   dim3(256), 0, stream>>>(W_enc, Wencbf, H_ * H_);
  cvt_k<<<dim3((V_ * H_) / 256),   dim3(256), 0, stream>>>(W_out, Woutbf, V_ * H_);
  cvt4_k<<<dim3((B_ * VIS_ / 4) / 256), dim3(256), 0, stream>>>(visual, visbf, B_ * VIS_ / 4);

  // zero split-K accumulators
  fill_f_k<<<dim3(BH / 256), dim3(256), 0, stream>>>(vf, 0.f, BH);
  fill_f_k<<<dim3(BH / 256), dim3(256), 0, stream>>>(tencf, 0.f, BH);
  fill_f_k<<<dim3(BH / 256), dim3(256), 0, stream>>>(hatt, 0.f, BH);

  // visual projection: vf += visbf . Wvis^T   (split-K 8)
  gemm_splitk_k<<<dim3(H_ / 128, B_ / 128, 8), dim3(256), 0, stream>>>(
      visbf, VIS_, Wvisbf, VIS_, VIS_ / 8, vf, H_);
  rownorm_f2b_k<<<dim3(B_), dim3(256), 0, stream>>>(vf, vbf, H_);

  // encoder LSTM
  fill_bf_k<<<dim3(BH / 256), dim3(256), 0, stream>>>(henc0, f2bf_h(0.1f), BH);
  fill_f_k<<<dim3(BH / 256), dim3(256), 0, stream>>>(cenc, 0.1f, BH);
  for (int t = 0; t < L_; ++t) {
    ushortT* hin  = (t & 1) ? henc1 : henc0;
    ushortT* hout = (t & 1) ? henc0 : henc1;
    lstm2_k<<<dim3(G4_ / 64, B_ / 256), dim3(256), 0, stream>>>(
        hin, Whhbf, xs_enc + (size_t)t * B_ * EP_, Wihbf, biasc,
        cenc, hout, selbf, lens, t);
  }

  // enc linear (split-K 4) + bias/relu/norm
  gemm_splitk_k<<<dim3(H_ / 128, B_ / 128, 4), dim3(256), 0, stream>>>(
      selbf, H_, Wencbf, H_, H_ / 4, tencf, H_);
  bias_relu_rownorm_k<<<dim3(B_), dim3(256), 0, stream>>>(tencf, b_enc, tencbf, H_);

  // attention
  gemm_bf16_k<<<dim3(B_ / 128, B_ / 128), dim3(256), 0, stream>>>(
      tencbf, H_, H_, vbf, H_, Pbf, B_);
  softmax_bf_rows_k<<<dim3(B_), dim3(256), 0, stream>>>(Pbf);
  transpose_bf_k<<<dim3(H_ / 32, B_ / 32), dim3(256), 0, stream>>>(vbf, Vtbf, B_, H_);
  gemm_splitk_k<<<dim3(H_ / 128, B_ / 128, 8), dim3(256), 0, stream>>>(
      Pbf, B_, Vtbf, B_, B_ / 8, hatt, H_);
  rownorm_fcb_k<<<dim3(B_), dim3(256), 0, stream>>>(hatt, hdec0, cdec, H_);

  // decoder LSTM + fused loss
  for (int t = 0; t < L_; ++t) {
    ushortT* hin  = (t & 1) ? hdec1 : hdec0;
    ushortT* hout = (t & 1) ? hdec0 : hdec1;
    lstm2_k<<<dim3(G4_ / 64, B_ / 256), dim3(256), 0, stream>>>(
        hin, Whhbf, xs_dec + (size_t)t * B_ * EP_, Wihbf, biasc,
        cdec, hout, nullptr, nullptr, t);
    dec_loss2_k<<<dim3(B_ / 16), dim3(256), 0, stream>>>(hout, Woutbf, text, t, out);
  }
}

// Round 5
// 1506.509 us; speedup vs baseline: 1.0352x; 1.0352x over previous
//
#include <hip/hip_runtime.h>
#include <math.h>

#define B_    4096
#define L_    16
#define E_    50
#define EP_   64
#define H_    512
#define G4_   2048
#define V_    128
#define VIS_  2048

typedef unsigned short ushortT;
typedef ushortT ushort8 __attribute__((ext_vector_type(8)));
typedef ushortT ushort4v __attribute__((ext_vector_type(4)));
typedef short   short8  __attribute__((ext_vector_type(8)));
typedef float   f32x4   __attribute__((ext_vector_type(4)));

__device__ __forceinline__ ushortT f2bf(float f) {
  union { float f; unsigned u; } v; v.f = f;
  unsigned u = v.u;
  u += 0x7fffu + ((u >> 16) & 1u);
  return (ushortT)(u >> 16);
}
__device__ __forceinline__ float bf2f(ushortT h) {
  union { unsigned u; float f; } v; v.u = ((unsigned)h) << 16;
  return v.f;
}
static inline ushortT f2bf_h(float f) {
  union { float f; unsigned u; } v; v.f = f;
  unsigned u = v.u;
  u += 0x7fffu + ((u >> 16) & 1u);
  return (ushortT)(u >> 16);
}

// ---------------------------------------------------------------- prep
__global__ void lengths_k(const int* __restrict__ text, int* __restrict__ lens) {
  int b = blockIdx.x * blockDim.x + threadIdx.x;
  if (b < B_) {
    int c = 0;
    for (int t = 0; t < L_; ++t) c += (text[b * L_ + t] != 0) ? 1 : 0;
    lens[b] = c;
  }
}

__global__ void stage_embs_k(const int* __restrict__ text, const float* __restrict__ emb,
                             ushortT* __restrict__ xs_enc, ushortT* __restrict__ xs_dec) {
  int idx = blockIdx.x * blockDim.x + threadIdx.x;
  const int total = L_ * B_ * EP_;
  if (idx >= total) return;
  int e = idx & 63;
  int r = idx >> 6;
  int b = r % B_;
  int t = r / B_;
  ushortT ve = 0, vd = 0;
  if (e < E_) {
    int id_enc = text[b * L_ + t];
    int id_dec = (t == 0) ? 0 : text[b * L_ + t - 1];
    ve = f2bf(emb[id_enc * E_ + e]);
    vd = f2bf(emb[id_dec * E_ + e]);
  }
  xs_enc[idx] = ve;
  xs_dec[idx] = vd;
}

// gate-interleaved: new row p = 4*j + q  <-  old row q*H + j  (q: i,f,g,o)
__global__ void prep_whh_k(const float* __restrict__ W, ushortT* __restrict__ D) {
  int idx = blockIdx.x * 256 + threadIdx.x;
  if (idx >= G4_ * H_) return;
  int k = idx & (H_ - 1), p = idx >> 9;
  int j = p >> 2, q = p & 3;
  D[idx] = f2bf(W[(size_t)(q * H_ + j) * H_ + k]);
}
__global__ void prep_wih_k(const float* __restrict__ W, ushortT* __restrict__ D) {
  int idx = blockIdx.x * 256 + threadIdx.x;
  if (idx >= G4_ * EP_) return;
  int k = idx & 63, p = idx >> 6;
  int j = p >> 2, q = p & 3;
  D[idx] = (k < E_) ? f2bf(W[(size_t)(q * H_ + j) * E_ + k]) : (ushortT)0;
}
__global__ void prep_bias_k(const float* __restrict__ bi, const float* __restrict__ bh,
                            float* __restrict__ D) {
  int p = blockIdx.x * 256 + threadIdx.x;
  if (p >= G4_) return;
  int j = p >> 2, q = p & 3;
  int o = q * H_ + j;
  D[p] = bi[o] + bh[o];
}
__global__ void cvt_k(const float* __restrict__ s, ushortT* __restrict__ d, int n) {
  int i = blockIdx.x * 256 + threadIdx.x;
  if (i < n) d[i] = f2bf(s[i]);
}
__global__ void cvt4_k(const float* __restrict__ s, ushortT* __restrict__ d, int n4) {
  int i = blockIdx.x * 256 + threadIdx.x;
  if (i >= n4) return;
  float4 v = ((const float4*)s)[i];
  ushort4v o;
  o[0] = f2bf(v.x); o[1] = f2bf(v.y); o[2] = f2bf(v.z); o[3] = f2bf(v.w);
  ((ushort4v*)d)[i] = o;
}
__global__ void fill_bf_k(ushortT* __restrict__ p, ushortT v, int n) {
  int i = blockIdx.x * blockDim.x + threadIdx.x;
  if (i < n) p[i] = v;
}
__global__ void fill_f_k(float* __restrict__ p, float v, int n) {
  int i = blockIdx.x * blockDim.x + threadIdx.x;
  if (i < n) p[i] = v;
}

// ---------------------------------------------------------------- weights-slice GEMM
// block = 256 M-rows x 64 N-cols; K-chunk = 512 per z-block (kbeg = z*512).
// B-slice (64 rows x 512) staged once into LDS in fragment order; barrier-free
// K-loop with A-fragments direct from global/L2. Output: bf16 direct (Cb, z==1)
// or fp32 partial buffer Cf + z*Mtot*ldc (disjoint per z — NO atomics).
__global__ __launch_bounds__(256, 2)
void gemm_ws_k(const ushortT* __restrict__ A, int lda,
               const ushortT* __restrict__ B, int ldb,
               float* __restrict__ Cf, ushortT* __restrict__ Cb,
               int ldc, int Mtot) {
  __shared__ ushortT wlds[64 * 512];          // 64 KB
  const int tid = threadIdx.x;
  const int n0 = blockIdx.x * 64;
  const int m0 = blockIdx.y * 256;
  const int kbeg = blockIdx.z * 512;
  const int lane = tid & 63, wave = tid >> 6;
  const int am = lane & 15, ak = (lane >> 4) * 8;
  const int wrow = m0 + wave * 64;

  // stage B-slice in fragment order: frag (ks, ni) at ((ks*4+ni)*64+ln)*8
#pragma unroll
  for (int i = 0; i < 16; ++i) {
    int idx = i * 256 + tid;                  // 0..4095
    int ks = idx >> 8;
    int rem = idx & 255;
    int ni = rem >> 6, ln = rem & 63;
    int row = n0 + ni * 16 + (ln & 15);
    int kc = (ln >> 4) * 8;
    *(ushort8*)(&wlds[idx * 8]) = *(const ushort8*)(&B[(size_t)row * ldb + kbeg + ks * 32 + kc]);
  }
  __syncthreads();

  f32x4 acc[4][4];
#pragma unroll
  for (int i = 0; i < 4; ++i)
#pragma unroll
    for (int j = 0; j < 4; ++j)
#pragma unroll
      for (int r = 0; r < 4; ++r) acc[i][j][r] = 0.f;

#pragma unroll 4
  for (int ks = 0; ks < 16; ++ks) {
    short8 a[4];
#pragma unroll
    for (int mi = 0; mi < 4; ++mi)
      a[mi] = *(const short8*)(&A[(size_t)(wrow + mi * 16 + am) * lda + kbeg + ks * 32 + ak]);
#pragma unroll
    for (int ni = 0; ni < 4; ++ni) {
      short8 b = *(const short8*)(&wlds[((ks * 4 + ni) * 64 + lane) * 8]);
#pragma unroll
      for (int mi = 0; mi < 4; ++mi)
        acc[mi][ni] = __builtin_amdgcn_mfma_f32_16x16x32_bf16(a[mi], b, acc[mi][ni], 0, 0, 0);
    }
  }

  if (Cb) {
#pragma unroll
    for (int mi = 0; mi < 4; ++mi)
#pragma unroll
      for (int r = 0; r < 4; ++r) {
        int m = wrow + mi * 16 + (lane >> 4) * 4 + r;
#pragma unroll
        for (int ni = 0; ni < 4; ++ni)
          Cb[(size_t)m * ldc + n0 + ni * 16 + am] = f2bf(acc[mi][ni][r]);
      }
  } else {
    float* Cz = Cf + (size_t)blockIdx.z * Mtot * ldc;
#pragma unroll
    for (int mi = 0; mi < 4; ++mi)
#pragma unroll
      for (int r = 0; r < 4; ++r) {
        int m = wrow + mi * 16 + (lane >> 4) * 4 + r;
#pragma unroll
        for (int ni = 0; ni < 4; ++ni)
          Cz[(size_t)m * ldc + n0 + ni * 16 + am] = acc[mi][ni][r];
      }
  }
}

// ---------------------------------------------------------------- reduce partials + (bias/relu) + rownorm
// parts: nparts buffers of [B_,H_] fp32 at stride B_*H_. out bf16 (+ optional fp32 copy).
__global__ void reduce_norm_k(const float* __restrict__ parts, int nparts,
                              const float* __restrict__ bias, int relu,
                              ushortT* __restrict__ outb, float* __restrict__ outc) {
  int b = blockIdx.x, tid = threadIdx.x;
  float v[2];
  float ss = 0.f;
#pragma unroll
  for (int l = 0; l < 2; ++l) {
    int i = tid + l * 256;
    float s = 0.f;
    for (int p = 0; p < nparts; ++p)
      s += parts[(size_t)p * B_ * H_ + (size_t)b * H_ + i];
    if (bias) s += bias[i];
    if (relu) s = fmaxf(s, 0.f);
    v[l] = s;
    ss += s * s;
  }
  __shared__ float red[256];
  red[tid] = ss; __syncthreads();
  for (int st = 128; st > 0; st >>= 1) { if (tid < st) red[tid] += red[tid + st]; __syncthreads(); }
  float inv = 1.f / sqrtf(red[0]);
#pragma unroll
  for (int l = 0; l < 2; ++l) {
    int i = tid + l * 256;
    float x = v[l] * inv;
    outb[(size_t)b * H_ + i] = f2bf(x);
    if (outc) outc[(size_t)b * H_ + i] = x;
  }
}

// ---------------------------------------------------------------- barrier-free fused LSTM step
__global__ __launch_bounds__(256, 2)
void lstm2_k(const ushortT* __restrict__ hin, const ushortT* __restrict__ Whh,
             const ushortT* __restrict__ xs,  const ushortT* __restrict__ Wih,
             const float* __restrict__ biasc,
             float* __restrict__ c, ushortT* __restrict__ hout,
             ushortT* __restrict__ sel, const int* __restrict__ lens, int t) {
  __shared__ ushortT wlds[18 * 4 * 64 * 8];   // 73728 B
  const int tid = threadIdx.x;
  const int n0 = blockIdx.x * 64;             // gate-col base
  const int m0 = blockIdx.y * 256;            // batch-row base
  const int lane = tid & 63, wave = tid >> 6;
  const int am = lane & 15, ak = (lane >> 4) * 8;
  const int wrow = m0 + wave * 64;

#pragma unroll
  for (int i = 0; i < 18; ++i) {
    int idx = i * 256 + tid;                  // 0..4607
    int ks = idx >> 8;
    int rem = idx & 255;
    int ni = rem >> 6, ln = rem & 63;
    int row = n0 + ni * 16 + (ln & 15);
    int kc = (ln >> 4) * 8;
    ushort8 vv;
    if (ks < 16) vv = *(const ushort8*)(&Whh[(size_t)row * H_ + ks * 32 + kc]);
    else         vv = *(const ushort8*)(&Wih[(size_t)row * EP_ + (ks - 16) * 32 + kc]);
    *(ushort8*)(&wlds[(size_t)idx * 8]) = vv;
  }
  __syncthreads();

  f32x4 acc[4][4];
#pragma unroll
  for (int i = 0; i < 4; ++i)
#pragma unroll
    for (int j = 0; j < 4; ++j)
#pragma unroll
      for (int r = 0; r < 4; ++r) acc[i][j][r] = 0.f;

#pragma unroll 4
  for (int ks = 0; ks < 16; ++ks) {
    short8 a[4];
#pragma unroll
    for (int mi = 0; mi < 4; ++mi)
      a[mi] = *(const short8*)(&hin[(size_t)(wrow + mi * 16 + am) * H_ + ks * 32 + ak]);
#pragma unroll
    for (int ni = 0; ni < 4; ++ni) {
      short8 b = *(const short8*)(&wlds[((ks * 4 + ni) * 64 + lane) * 8]);
#pragma unroll
      for (int mi = 0; mi < 4; ++mi)
        acc[mi][ni] = __builtin_amdgcn_mfma_f32_16x16x32_bf16(a[mi], b, acc[mi][ni], 0, 0, 0);
    }
  }
#pragma unroll
  for (int ks = 0; ks < 2; ++ks) {
    short8 a[4];
#pragma unroll
    for (int mi = 0; mi < 4; ++mi)
      a[mi] = *(const short8*)(&xs[(size_t)(wrow + mi * 16 + am) * EP_ + ks * 32 + ak]);
#pragma unroll
    for (int ni = 0; ni < 4; ++ni) {
      short8 b = *(const short8*)(&wlds[(((16 + ks) * 4 + ni) * 64 + lane) * 8]);
#pragma unroll
      for (int mi = 0; mi < 4; ++mi)
        acc[mi][ni] = __builtin_amdgcn_mfma_f32_16x16x32_bf16(a[mi], b, acc[mi][ni], 0, 0, 0);
    }
  }

  __syncthreads();                            // all waves done reading wlds
  float* gw = (float*)wlds + wave * 64 * 68;
#pragma unroll
  for (int mi = 0; mi < 4; ++mi)
#pragma unroll
    for (int r = 0; r < 4; ++r) {
      int rowL = mi * 16 + (lane >> 4) * 4 + r;
#pragma unroll
      for (int ni = 0; ni < 4; ++ni)
        gw[rowL * 68 + ni * 16 + am] = acc[mi][ni][r];
    }
  const int jg0 = n0 >> 2;
#pragma unroll
  for (int p = 0; p < 16; ++p) {
    int idx = p * 64 + lane;
    int rowL = idx >> 4, j = idx & 15;
    f32x4 g  = *(const f32x4*)(&gw[rowL * 68 + j * 4]);
    f32x4 bb = *(const f32x4*)(&biasc[(jg0 + j) * 4]);
    int brow = wrow + rowL;
    size_t ci = (size_t)brow * H_ + jg0 + j;
    float ig = g[0] + bb[0], fg = g[1] + bb[1], gg = g[2] + bb[2], og = g[3] + bb[3];
    float si = 1.f / (1.f + expf(-ig));
    float sf = 1.f / (1.f + expf(-fg));
    float so = 1.f / (1.f + expf(-og));
    float cn = sf * c[ci] + si * tanhf(gg);
    float hn = so * tanhf(cn);
    c[ci] = cn;
    hout[ci] = f2bf(hn);
    if (sel) {
      int len = lens[brow];
      int eff = (len == 0) ? L_ : len;
      if (t == eff - 1) sel[ci] = f2bf(hn);
    }
  }
}

// ---------------------------------------------------------------- decoder logits + NLL
__global__ __launch_bounds__(256)
void dec_loss2_k(const ushortT* __restrict__ h, const ushortT* __restrict__ Wout,
                 const int* __restrict__ text, int t, float* __restrict__ out) {
  __shared__ float pbuf[4 * 16 * 132];
  const int tid = threadIdx.x;
  const int row0 = blockIdx.x * 16;
  const int lane = tid & 63, wave = tid >> 6;
  const int am = lane & 15, ak = (lane >> 4) * 8;

  f32x4 acc[8];
#pragma unroll
  for (int i = 0; i < 8; ++i)
#pragma unroll
    for (int r = 0; r < 4; ++r) acc[i][r] = 0.f;

#pragma unroll
  for (int ks = 0; ks < 4; ++ks) {
    int kk = wave * 128 + ks * 32;
    short8 a = *(const short8*)(&h[(size_t)(row0 + am) * H_ + kk + ak]);
#pragma unroll
    for (int nf = 0; nf < 8; ++nf) {
      short8 b = *(const short8*)(&Wout[(size_t)(nf * 16 + am) * H_ + kk + ak]);
      acc[nf] = __builtin_amdgcn_mfma_f32_16x16x32_bf16(a, b, acc[nf], 0, 0, 0);
    }
  }
#pragma unroll
  for (int nf = 0; nf < 8; ++nf)
#pragma unroll
    for (int r = 0; r < 4; ++r) {
      int rowL = (lane >> 4) * 4 + r;
      pbuf[(wave * 16 + rowL) * 132 + nf * 16 + am] = acc[nf][r];
    }
  __syncthreads();

  int row = tid >> 4, lp = tid & 15;
  f32x4 s0, s1;
#pragma unroll
  for (int r = 0; r < 4; ++r) { s0[r] = 0.f; s1[r] = 0.f; }
#pragma unroll
  for (int wv = 0; wv < 4; ++wv) {
    s0 += *(const f32x4*)(&pbuf[(wv * 16 + row) * 132 + lp * 8]);
    s1 += *(const f32x4*)(&pbuf[(wv * 16 + row) * 132 + lp * 8 + 4]);
  }
  float mx = s0[0];
#pragma unroll
  for (int r = 1; r < 4; ++r) mx = fmaxf(mx, s0[r]);
#pragma unroll
  for (int r = 0; r < 4; ++r) mx = fmaxf(mx, s1[r]);
#pragma unroll
  for (int d = 1; d < 16; d <<= 1) mx = fmaxf(mx, __shfl_xor(mx, d));
  float sum = 0.f;
#pragma unroll
  for (int r = 0; r < 4; ++r) sum += expf(s0[r] - mx) + expf(s1[r] - mx);
#pragma unroll
  for (int d = 1; d < 16; d <<= 1) sum += __shfl_xor(sum, d);
  float lse = mx + logf(sum);
  int b = row0 + row;
  int tgt = text[b * L_ + t];
  if ((tgt >> 3) == lp) {
    float lv = (tgt & 4) ? s1[tgt & 3] : s0[tgt & 3];
    float loss = (lse - lv) * (1.f / (float)L_);
    if (t == 0) out[b] = loss;
    else out[b] += loss;
  }
}

// ---------------------------------------------------------------- softmax / transpose
__global__ __launch_bounds__(256)
void softmax_bf_rows_k(ushortT* __restrict__ P) {
  int r = blockIdx.x, tid = threadIdx.x;
  ushortT* row = P + (size_t)r * B_;
  float xv[16];
  float m = -1e30f;
#pragma unroll
  for (int l = 0; l < 16; ++l) { float v = bf2f(row[tid + l * 256]); xv[l] = v; m = fmaxf(m, v); }
  __shared__ float red[256];
  red[tid] = m; __syncthreads();
  for (int st = 128; st > 0; st >>= 1) { if (tid < st) red[tid] = fmaxf(red[tid], red[tid + st]); __syncthreads(); }
  m = red[0]; __syncthreads();
  float s = 0.f;
#pragma unroll
  for (int l = 0; l < 16; ++l) { float e = expf(xv[l] - m); xv[l] = e; s += e; }
  red[tid] = s; __syncthreads();
  for (int st = 128; st > 0; st >>= 1) { if (tid < st) red[tid] += red[tid + st]; __syncthreads(); }
  float inv = 1.f / red[0];
#pragma unroll
  for (int l = 0; l < 16; ++l) row[tid + l * 256] = f2bf(xv[l] * inv);
}

__global__ void transpose_bf_k(const ushortT* __restrict__ in, ushortT* __restrict__ out,
                               int R, int Ccols) {
  __shared__ ushortT tile[32][33];
  int c0 = blockIdx.x * 32, r0 = blockIdx.y * 32;
  int tx = threadIdx.x & 31, ty = threadIdx.x >> 5;
  for (int i = ty; i < 32; i += 8) tile[i][tx] = in[(size_t)(r0 + i) * Ccols + c0 + tx];
  __syncthreads();
  for (int i = ty; i < 32; i += 8) out[(size_t)(c0 + i) * R + r0 + tx] = tile[tx][i];
}

// ================================================================ launch
extern "C" void kernel_launch(void* const* d_in, const int* in_sizes, int n_in,
                              void* d_out, int out_size, void* d_ws, size_t ws_size,
                              hipStream_t stream) {
  const float* visual = (const float*)d_in[0];
  const int*   text   = (const int*)  d_in[1];
  const float* emb    = (const float*)d_in[2];
  const float* W_ih   = (const float*)d_in[3];
  const float* W_hh   = (const float*)d_in[4];
  const float* b_ih   = (const float*)d_in[5];
  const float* b_hh   = (const float*)d_in[6];
  const float* W_enc  = (const float*)d_in[7];
  const float* b_enc  = (const float*)d_in[8];
  const float* W_out  = (const float*)d_in[9];
  const float* W_vis  = (const float*)d_in[10];
  float* out = (float*)d_out;

  char* w = (char*)d_ws;
  auto alloc = [&](size_t bytes) { char* p = w; w += (bytes + 255) & ~(size_t)255; return p; };
  ushortT* xs_enc  = (ushortT*)alloc((size_t)L_ * B_ * EP_ * 2);
  ushortT* xs_dec  = (ushortT*)alloc((size_t)L_ * B_ * EP_ * 2);
  ushortT* Whhbf   = (ushortT*)alloc((size_t)G4_ * H_ * 2);
  ushortT* Wihbf   = (ushortT*)alloc((size_t)G4_ * EP_ * 2);
  float*   biasc   = (float*)  alloc((size_t)G4_ * 4);
  ushortT* Wvisbf  = (ushortT*)alloc((size_t)H_ * VIS_ * 2);
  ushortT* Wencbf  = (ushortT*)alloc((size_t)H_ * H_ * 2);
  ushortT* Woutbf  = (ushortT*)alloc((size_t)V_ * H_ * 2);
  ushortT* visbf   = (ushortT*)alloc((size_t)B_ * VIS_ * 2);
  ushortT* henc0   = (ushortT*)alloc((size_t)B_ * H_ * 2);
  ushortT* henc1   = (ushortT*)alloc((size_t)B_ * H_ * 2);
  float*   cenc    = (float*)  alloc((size_t)B_ * H_ * 4);
  ushortT* selbf   = (ushortT*)alloc((size_t)B_ * H_ * 2);
  ushortT* vbf     = (ushortT*)alloc((size_t)B_ * H_ * 2);
  ushortT* tencbf  = (ushortT*)alloc((size_t)B_ * H_ * 2);
  ushortT* Pbf     = (ushortT*)alloc((size_t)B_ * B_ * 2);
  ushortT* Vtbf    = (ushortT*)alloc((size_t)H_ * B_ * 2);
  float*   cdec    = (float*)  alloc((size_t)B_ * H_ * 4);
  ushortT* hdec0   = (ushortT*)alloc((size_t)B_ * H_ * 2);
  ushortT* hdec1   = (ushortT*)alloc((size_t)B_ * H_ * 2);
  int*     lens    = (int*)    alloc((size_t)B_ * 4);
  float*   parts   = (float*)  alloc((size_t)8 * B_ * H_ * 4);   // 64 MB, reused

  const int BH = B_ * H_;

  lengths_k<<<dim3((B_ + 255) / 256), dim3(256), 0, stream>>>(text, lens);
  stage_embs_k<<<dim3((L_ * B_ * EP_) / 256), dim3(256), 0, stream>>>(text, emb, xs_enc, xs_dec);
  prep_whh_k<<<dim3((G4_ * H_) / 256), dim3(256), 0, stream>>>(W_hh, Whhbf);
  prep_wih_k<<<dim3((G4_ * EP_) / 256), dim3(256), 0, stream>>>(W_ih, Wihbf);
  prep_bias_k<<<dim3(G4_ / 256), dim3(256), 0, stream>>>(b_ih, b_hh, biasc);
  cvt_k<<<dim3((H_ * VIS_) / 256), dim3(256), 0, stream>>>(W_vis, Wvisbf, H_ * VIS_);
  cvt_k<<<dim3((H_ * H_) / 256),   dim3(256), 0, stream>>>(W_enc, Wencbf, H_ * H_);
  cvt_k<<<dim3((V_ * H_) / 256),   dim3(256), 0, stream>>>(W_out, Woutbf, V_ * H_);
  cvt4_k<<<dim3((B_ * VIS_ / 4) / 256), dim3(256), 0, stream>>>(visual, visbf, B_ * VIS_ / 4);

  // visual projection: z=4 partials, then reduce+norm -> vbf
  gemm_ws_k<<<dim3(H_ / 64, B_ / 256, 4), dim3(256), 0, stream>>>(
      visbf, VIS_, Wvisbf, VIS_, parts, nullptr, H_, B_);
  reduce_norm_k<<<dim3(B_), dim3(256), 0, stream>>>(parts, 4, nullptr, 0, vbf, nullptr);

  // encoder LSTM
  fill_bf_k<<<dim3(BH / 256), dim3(256), 0, stream>>>(henc0, f2bf_h(0.1f), BH);
  fill_f_k<<<dim3(BH / 256), dim3(256), 0, stream>>>(cenc, 0.1f, BH);
  for (int t = 0; t < L_; ++t) {
    ushortT* hin  = (t & 1) ? henc1 : henc0;
    ushortT* hout = (t & 1) ? henc0 : henc1;
    lstm2_k<<<dim3(G4_ / 64, B_ / 256), dim3(256), 0, stream>>>(
        hin, Whhbf, xs_enc + (size_t)t * B_ * EP_, Wihbf, biasc,
        cenc, hout, selbf, lens, t);
  }

  // enc linear (z=1) + bias/relu/norm -> tencbf
  gemm_ws_k<<<dim3(H_ / 64, B_ / 256, 1), dim3(256), 0, stream>>>(
      selbf, H_, Wencbf, H_, parts, nullptr, H_, B_);
  reduce_norm_k<<<dim3(B_), dim3(256), 0, stream>>>(parts, 1, b_enc, 1, tencbf, nullptr);

  // sims: P[j,i] = tenc_j . v_i  (bf16 direct out)
  gemm_ws_k<<<dim3(B_ / 64, B_ / 256, 1), dim3(256), 0, stream>>>(
      tencbf, H_, vbf, H_, nullptr, Pbf, B_, B_);
  softmax_bf_rows_k<<<dim3(B_), dim3(256), 0, stream>>>(Pbf);
  transpose_bf_k<<<dim3(H_ / 32, B_ / 32), dim3(256), 0, stream>>>(vbf, Vtbf, B_, H_);

  // PV: hatt = P . Vt^T  (z=8 partials) then reduce+norm -> hdec0 bf16 + cdec fp32
  gemm_ws_k<<<dim3(H_ / 64, B_ / 256, 8), dim3(256), 0, stream>>>(
      Pbf, B_, Vtbf, B_, parts, nullptr, H_, B_);
  reduce_norm_k<<<dim3(B_), dim3(256), 0, stream>>>(parts, 8, nullptr, 0, hdec0, cdec);

  // decoder LSTM + fused loss
  for (int t = 0; t < L_; ++t) {
    ushortT* hin  = (t & 1) ? hdec1 : hdec0;
    ushortT* hout = (t & 1) ? hdec0 : hdec1;
    lstm2_k<<<dim3(G4_ / 64, B_ / 256), dim3(256), 0, stream>>>(
        hin, Whhbf, xs_dec + (size_t)t * B_ * EP_, Wihbf, biasc,
        cdec, hout, nullptr, nullptr, t);
    dec_loss2_k<<<dim3(B_ / 16), dim3(256), 0, stream>>>(hout, Woutbf, text, t, out);
  }
}